// Round 9
// baseline (235.502 us; speedup 1.0000x reference)
//
#include <hip/hip_runtime.h>
#include <hip/hip_fp16.h>
#include <math.h>

#define N_NODES 50000
#define E_EDGES 800000
#define IN_C    128
#define HID     16
#define HEADS   8
#define OUT_C   64
#define NEG_SLOPE 0.2f
#define NSHARD  8
#define SHW     24   // per-shard ELL width; Poisson(~2)/shard, P(>=24) ~ 1e-12 total

typedef _Float16 half8 __attribute__((ext_vector_type(8)));
typedef float floatx4 __attribute__((ext_vector_type(4)));

// s_getreg imm encoding: (size-1)<<11 | offset<<6 | id ; HW_REG_XCC_ID = 20 (gfx940+)
#define XCC_ID_REG (((4 - 1) << 11) | 20)

__device__ __forceinline__ float lrelu_exp(float v) {
    v = v > 0.f ? v : NEG_SLOPE * v;
    return __expf(v);
}

// ---------- fused: layer-1 MFMA GEMM (+logits) on even blocks, sharded ELL fill on odd ----------
__global__ __launch_bounds__(256) void fused_gemm_fill(
    const float* __restrict__ X, const float* __restrict__ W, __half* __restrict__ H,
    const float* __restrict__ a_src, const float* __restrict__ a_dst,
    float* __restrict__ als, float* __restrict__ ald,
    const int* __restrict__ src, const int* __restrict__ dst,
    int* __restrict__ cursor, int* __restrict__ ell) {
    __shared__ _Float16 wT[IN_C * 136];  // W1^T fp16, stride 136 (16B-aligned frags, bank spread)
    const int bid = blockIdx.x;
    const int t = threadIdx.x;

    if (bid & 1) {
        // ---- fill role: XCD-local shard => single-writer cache lines, 8x less contention ----
        const int xcc = __builtin_amdgcn_s_getreg(XCC_ID_REG) & 7;
        int* cur = cursor + xcc * N_NODES;
        int* es = ell + (size_t)xcc * N_NODES * SHW;
        const int tid = (bid >> 1) * 256 + t;
        if (tid < E_EDGES / 4) {
            const int4 s4 = ((const int4*)src)[tid];
            const int4 d4 = ((const int4*)dst)[tid];
            const int p0 = atomicAdd(&cur[d4.x], 1);
            const int p1 = atomicAdd(&cur[d4.y], 1);
            const int p2 = atomicAdd(&cur[d4.z], 1);
            const int p3 = atomicAdd(&cur[d4.w], 1);
            if (p0 < SHW) es[d4.x * SHW + p0] = s4.x;
            if (p1 < SHW) es[d4.y * SHW + p1] = s4.y;
            if (p2 < SHW) es[d4.z * SHW + p2] = s4.z;
            if (p3 < SHW) es[d4.w * SHW + p3] = s4.w;
        }
        return;
    }

    // ---- gemm role: mfma_f32_16x16x32_f16, one wave = 16 rows x 128 cols ----
    for (int f = t * 4; f < IN_C * IN_C; f += 1024) {
        const float4 w4 = *(const float4*)&W[f];
        const int k = f >> 7, col = f & 127;
        wT[(col + 0) * 136 + k] = (_Float16)w4.x;
        wT[(col + 1) * 136 + k] = (_Float16)w4.y;
        wT[(col + 2) * 136 + k] = (_Float16)w4.z;
        wT[(col + 3) * 136 + k] = (_Float16)w4.w;
    }
    __syncthreads();

    const int wave = t >> 6, lane = t & 63;
    const int m = lane & 15, quad = lane >> 4;
    const int r0w = (bid >> 1) * 64 + wave * 16;
    int rl = r0w + m;
    if (rl >= N_NODES) rl = N_NODES - 1;  // clamp (dup read; stores guarded)
    const float* Xr = X + (size_t)rl * IN_C;

    floatx4 acc[8];
#pragma unroll
    for (int i = 0; i < 8; ++i) acc[i] = (floatx4){0.f, 0.f, 0.f, 0.f};

#pragma unroll
    for (int kc = 0; kc < 4; ++kc) {
        const int k8 = kc * 32 + quad * 8;
        // A frag: A[m=lane&15][k = quad*8 + j] (verified layout, m120)
        const float4 xa = *(const float4*)(Xr + k8);
        const float4 xb = *(const float4*)(Xr + k8 + 4);
        half8 a;
        a[0] = (_Float16)xa.x; a[1] = (_Float16)xa.y;
        a[2] = (_Float16)xa.z; a[3] = (_Float16)xa.w;
        a[4] = (_Float16)xb.x; a[5] = (_Float16)xb.y;
        a[6] = (_Float16)xb.z; a[7] = (_Float16)xb.w;
#pragma unroll
        for (int ct = 0; ct < 8; ++ct) {
            // B frag: B[k = quad*8 + j][n = lane&15], from transposed LDS = one b128
            const half8 b = *(const half8*)&wT[(ct * 16 + m) * 136 + k8];
            acc[ct] = __builtin_amdgcn_mfma_f32_16x16x32_f16(a, b, acc[ct], 0, 0, 0);
        }
    }

    // epilogue: h1 fp16 store + fused per-head logits (head == col-tile, HID==16)
    _Float16* Hh = (_Float16*)H;
#pragma unroll
    for (int ct = 0; ct < 8; ++ct) {
        const float asv = a_src[ct * 16 + m];
        const float adv = a_dst[ct * 16 + m];
#pragma unroll
        for (int r = 0; r < 4; ++r) {
            const int row = r0w + quad * 4 + r;  // C layout: col=lane&15, row=quad*4+reg
            const float c = acc[ct][r];
            float ps = c * asv, pd = c * adv;
            ps += __shfl_xor(ps, 1); pd += __shfl_xor(pd, 1);
            ps += __shfl_xor(ps, 2); pd += __shfl_xor(pd, 2);
            ps += __shfl_xor(ps, 4); pd += __shfl_xor(pd, 4);
            ps += __shfl_xor(ps, 8); pd += __shfl_xor(pd, 8);
            if (row < N_NODES) {
                Hh[(size_t)row * IN_C + ct * 16 + m] = (_Float16)c;
                if (m == 0) {
                    als[(size_t)row * HEADS + ct] = ps;
                    ald[(size_t)row * HEADS + ct] = pd;
                }
            }
        }
    }
}

// ---------- fused agg1 + gemm2 + logits2 over sharded ELL ----------
__global__ __launch_bounds__(256) void agg1_gemm2(
    const int* __restrict__ cnt, const int* __restrict__ ell,
    const float* __restrict__ als, const float* __restrict__ ald,
    const __half* __restrict__ H, const float* __restrict__ b,
    const float* __restrict__ W2, const float* __restrict__ a2_src,
    const float* __restrict__ a2_dst, __half* __restrict__ H2,
    float* __restrict__ als2, float* __restrict__ ald2) {
    __shared__ __half wsh[IN_C * OUT_C];   // 16 KB
    __shared__ float xrow[8 * 132];
    const int t = threadIdx.x;
    for (int f = t * 4; f < IN_C * OUT_C; f += 1024) {
        const float4 w4 = *(const float4*)&W2[f];
        *(__half2*)&wsh[f]     = __float22half2_rn(make_float2(w4.x, w4.y));
        *(__half2*)&wsh[f + 2] = __float22half2_rn(make_float2(w4.z, w4.w));
    }

    // ---- Phase A: agg1 gather (8 shards, predicated unroll-4) ----
    const int nl = t >> 5, tl = t & 31, h = tl >> 2, cg = tl & 3;
    const int n = blockIdx.x * 8 + nl;
    const float ad = ald[n * HEADS + h];
    float ssum;
    float4 acc;
    {
        const float w = lrelu_exp(als[n * HEADS + h] + ad);  // self-loop
        const __half2* hp = (const __half2*)(H + ((size_t)n * HEADS + h) * HID + cg * 4);
        const float2 a0 = __half22float2(hp[0]);
        const float2 a1 = __half22float2(hp[1]);
        ssum = w;
        acc = make_float4(w * a0.x, w * a0.y, w * a1.x, w * a1.y);
    }
    for (int sh = 0; sh < NSHARD; ++sh) {
        int deg = cnt[sh * N_NODES + n];
        deg = deg < SHW ? deg : SHW;
        const int* ep = ell + ((size_t)sh * N_NODES + (size_t)n) * SHW;
        for (int p = 0; p < deg; p += 4) {
            const int4 s4 = *(const int4*)(ep + p);
            const int i1 = (p + 1 < deg) ? s4.y : n;
            const int i2 = (p + 2 < deg) ? s4.z : n;
            const int i3 = (p + 3 < deg) ? s4.w : n;
            const float f1 = (p + 1 < deg) ? 1.f : 0.f;
            const float f2 = (p + 2 < deg) ? 1.f : 0.f;
            const float f3 = (p + 3 < deg) ? 1.f : 0.f;
            const float v0 = als[s4.x * HEADS + h];
            const float v1 = als[i1 * HEADS + h];
            const float v2 = als[i2 * HEADS + h];
            const float v3 = als[i3 * HEADS + h];
            const __half2* h0 = (const __half2*)(H + ((size_t)s4.x * HEADS + h) * HID + cg * 4);
            const __half2* h1 = (const __half2*)(H + ((size_t)i1 * HEADS + h) * HID + cg * 4);
            const __half2* h2 = (const __half2*)(H + ((size_t)i2 * HEADS + h) * HID + cg * 4);
            const __half2* h3 = (const __half2*)(H + ((size_t)i3 * HEADS + h) * HID + cg * 4);
            const __half2 m00 = h0[0], m01 = h0[1];
            const __half2 m10 = h1[0], m11 = h1[1];
            const __half2 m20 = h2[0], m21 = h2[1];
            const __half2 m30 = h3[0], m31 = h3[1];
            const float w0 = lrelu_exp(v0 + ad);
            const float w1 = lrelu_exp(v1 + ad) * f1;
            const float w2 = lrelu_exp(v2 + ad) * f2;
            const float w3 = lrelu_exp(v3 + ad) * f3;
            ssum += (w0 + w1) + (w2 + w3);
            float2 f;
            f = __half22float2(m00); acc.x += w0 * f.x; acc.y += w0 * f.y;
            f = __half22float2(m01); acc.z += w0 * f.x; acc.w += w0 * f.y;
            f = __half22float2(m10); acc.x += w1 * f.x; acc.y += w1 * f.y;
            f = __half22float2(m11); acc.z += w1 * f.x; acc.w += w1 * f.y;
            f = __half22float2(m20); acc.x += w2 * f.x; acc.y += w2 * f.y;
            f = __half22float2(m21); acc.z += w2 * f.x; acc.w += w2 * f.y;
            f = __half22float2(m30); acc.x += w3 * f.x; acc.y += w3 * f.y;
            f = __half22float2(m31); acc.z += w3 * f.x; acc.w += w3 * f.y;
        }
    }
    const float inv = 1.f / (ssum + 1e-16f);
    const int c0 = h * HID + cg * 4;
    float4 r;
    r.x = acc.x * inv + b[c0 + 0];
    r.y = acc.y * inv + b[c0 + 1];
    r.z = acc.z * inv + b[c0 + 2];
    r.w = acc.w * inv + b[c0 + 3];
    r.x = r.x > 0.f ? r.x : 0.f;
    r.y = r.y > 0.f ? r.y : 0.f;
    r.z = r.z > 0.f ? r.z : 0.f;
    r.w = r.w > 0.f ? r.w : 0.f;
    float* xr = &xrow[nl * 132 + c0];
    xr[0] = r.x; xr[1] = r.y; xr[2] = r.z; xr[3] = r.w;

    __syncthreads();

    // ---- Phase B: h2 = xrow @ W2 (2 cols/thread) + fused logits2 ----
    const int j0 = (t & 31) * 2;
    const int ng = t >> 5;
    const int n2 = blockIdx.x * 8 + ng;
    const float a2s0 = a2_src[j0], a2s1 = a2_src[j0 + 1];
    const float a2d0 = a2_dst[j0], a2d1 = a2_dst[j0 + 1];
    float o0 = 0.f, o1 = 0.f;
    const float* xb = &xrow[ng * 132];
#pragma unroll 4
    for (int c = 0; c < IN_C; c += 4) {
        const float4 xv = *(const float4*)&xb[c];
        const float2 wa = __half22float2(*(const __half2*)&wsh[(c + 0) * OUT_C + j0]);
        const float2 wb = __half22float2(*(const __half2*)&wsh[(c + 1) * OUT_C + j0]);
        const float2 wc = __half22float2(*(const __half2*)&wsh[(c + 2) * OUT_C + j0]);
        const float2 wd = __half22float2(*(const __half2*)&wsh[(c + 3) * OUT_C + j0]);
        o0 += xv.x * wa.x + xv.y * wb.x + xv.z * wc.x + xv.w * wd.x;
        o1 += xv.x * wa.y + xv.y * wb.y + xv.z * wc.y + xv.w * wd.y;
    }
    float ps = o0 * a2s0 + o1 * a2s1;
    float pd = o0 * a2d0 + o1 * a2d1;
#pragma unroll
    for (int off = 1; off < 32; off <<= 1) {
        ps += __shfl_xor(ps, off);
        pd += __shfl_xor(pd, off);
    }
    *(__half2*)(H2 + (size_t)n2 * OUT_C + j0) = __float22half2_rn(make_float2(o0, o1));
    if ((t & 31) == 0) {
        als2[n2] = ps;
        ald2[n2] = pd;
    }
}

// ---------- agg2 over sharded ELL + analytic self-loop ----------
__global__ void agg2(const int* __restrict__ cnt, const int* __restrict__ ell,
                     const float* __restrict__ als, const float* __restrict__ ald,
                     const __half* __restrict__ H, const float* __restrict__ b,
                     float* __restrict__ out) {
    int i = blockIdx.x * blockDim.x + threadIdx.x;
    if (i >= N_NODES * 16) return;
    const int n = i >> 4, cg = i & 15;
    const float ad = ald[n];
    float ssum;
    float4 acc;
    {
        const float w = lrelu_exp(als[n] + ad);
        const __half2* hp = (const __half2*)(H + (size_t)n * OUT_C + cg * 4);
        const float2 a0 = __half22float2(hp[0]);
        const float2 a1 = __half22float2(hp[1]);
        ssum = w;
        acc = make_float4(w * a0.x, w * a0.y, w * a1.x, w * a1.y);
    }
    for (int sh = 0; sh < NSHARD; ++sh) {
        int deg = cnt[sh * N_NODES + n];
        deg = deg < SHW ? deg : SHW;
        const int* ep = ell + ((size_t)sh * N_NODES + (size_t)n) * SHW;
        for (int p = 0; p < deg; p += 4) {
            const int4 s4 = *(const int4*)(ep + p);
            const int i1 = (p + 1 < deg) ? s4.y : n;
            const int i2 = (p + 2 < deg) ? s4.z : n;
            const int i3 = (p + 3 < deg) ? s4.w : n;
            const float f1 = (p + 1 < deg) ? 1.f : 0.f;
            const float f2 = (p + 2 < deg) ? 1.f : 0.f;
            const float f3 = (p + 3 < deg) ? 1.f : 0.f;
            const float v0 = als[s4.x];
            const float v1 = als[i1];
            const float v2 = als[i2];
            const float v3 = als[i3];
            const __half2* h0 = (const __half2*)(H + (size_t)s4.x * OUT_C + cg * 4);
            const __half2* h1 = (const __half2*)(H + (size_t)i1 * OUT_C + cg * 4);
            const __half2* h2 = (const __half2*)(H + (size_t)i2 * OUT_C + cg * 4);
            const __half2* h3 = (const __half2*)(H + (size_t)i3 * OUT_C + cg * 4);
            const __half2 m00 = h0[0], m01 = h0[1];
            const __half2 m10 = h1[0], m11 = h1[1];
            const __half2 m20 = h2[0], m21 = h2[1];
            const __half2 m30 = h3[0], m31 = h3[1];
            const float w0 = lrelu_exp(v0 + ad);
            const float w1 = lrelu_exp(v1 + ad) * f1;
            const float w2 = lrelu_exp(v2 + ad) * f2;
            const float w3 = lrelu_exp(v3 + ad) * f3;
            ssum += (w0 + w1) + (w2 + w3);
            float2 f;
            f = __half22float2(m00); acc.x += w0 * f.x; acc.y += w0 * f.y;
            f = __half22float2(m01); acc.z += w0 * f.x; acc.w += w0 * f.y;
            f = __half22float2(m10); acc.x += w1 * f.x; acc.y += w1 * f.y;
            f = __half22float2(m11); acc.z += w1 * f.x; acc.w += w1 * f.y;
            f = __half22float2(m20); acc.x += w2 * f.x; acc.y += w2 * f.y;
            f = __half22float2(m21); acc.z += w2 * f.x; acc.w += w2 * f.y;
            f = __half22float2(m30); acc.x += w3 * f.x; acc.y += w3 * f.y;
            f = __half22float2(m31); acc.z += w3 * f.x; acc.w += w3 * f.y;
        }
    }
    const float inv = 1.f / (ssum + 1e-16f);
    const int c0 = cg * 4;
    float4 r;
    r.x = acc.x * inv + b[c0 + 0];
    r.y = acc.y * inv + b[c0 + 1];
    r.z = acc.z * inv + b[c0 + 2];
    r.w = acc.w * inv + b[c0 + 3];
    *(float4*)(out + (size_t)n * OUT_C + c0) = r;
}

extern "C" void kernel_launch(void* const* d_in, const int* in_sizes, int n_in,
                              void* d_out, int out_size, void* d_ws, size_t ws_size,
                              hipStream_t stream) {
    const float* x      = (const float*)d_in[0];
    const int*   ei     = (const int*)d_in[1];
    const float* W1     = (const float*)d_in[2];
    const float* a1_src = (const float*)d_in[3];
    const float* a1_dst = (const float*)d_in[4];
    const float* b1     = (const float*)d_in[5];
    const float* W2     = (const float*)d_in[6];
    const float* a2_src = (const float*)d_in[7];
    const float* a2_dst = (const float*)d_in[8];
    const float* b2     = (const float*)d_in[9];
    const int* src = ei;
    const int* dst = ei + E_EDGES;
    float* outp = (float*)d_out;

    // ---- workspace layout (all offsets 16B-aligned) ----
    char* wsb = (char*)d_ws;
    __half* h1   = (__half*)wsb;                                 // N*128 f16
    __half* h2   = h1 + (size_t)N_NODES * IN_C;                  // N*64  f16
    float*  als1 = (float*)(h2 + (size_t)N_NODES * OUT_C);       // N*8
    float*  ald1 = als1 + N_NODES * HEADS;                       // N*8
    float*  als2 = ald1 + N_NODES * HEADS;                       // N
    float*  ald2 = als2 + N_NODES;                               // N
    int*    cursor = (int*)(ald2 + N_NODES);                     // 8*N [zero]
    int*    ell    = cursor + NSHARD * N_NODES;                  // 8*N*SHW

    hipMemsetAsync(cursor, 0, NSHARD * N_NODES * sizeof(int), stream);

    // ---- fused layer-1 MFMA GEMM + sharded ELL fill ----
    {
        const int gemm_blocks = (N_NODES + 63) / 64;  // 782 (== fill blocks)
        fused_gemm_fill<<<gemm_blocks * 2, 256, 0, stream>>>(
            x, W1, h1, a1_src, a1_dst, als1, ald1, src, dst, cursor, ell);
    }

    // ---- fused agg1 + gemm2 + logits2 ----
    agg1_gemm2<<<N_NODES / 8, 256, 0, stream>>>(
        cursor, ell, als1, ald1, h1, b1, W2, a2_src, a2_dst, h2, als2, ald2);

    // ---- layer-2 aggregation -> output ----
    {
        int n = N_NODES * 16;
        agg2<<<(n + 255) / 256, 256, 0, stream>>>(cursor, ell, als2, ald2, h2, b2, outp);
    }
}

// Round 10
// 223.178 us; speedup vs baseline: 1.0552x; 1.0552x over previous
//
#include <hip/hip_runtime.h>
#include <hip/hip_fp16.h>
#include <math.h>

#define N_NODES 50000
#define E_EDGES 800000
#define IN_C    128
#define HID     16
#define HEADS   8
#define OUT_C   64
#define NEG_SLOPE 0.2f
#define NSHARD  8
#define SHW     24   // per-shard ELL width
#define CELLW   64   // compacted ELL width (total deg <= ~45 verified R2-R8)

typedef _Float16 half8 __attribute__((ext_vector_type(8)));
typedef float floatx4 __attribute__((ext_vector_type(4)));

// s_getreg imm encoding: (size-1)<<11 | offset<<6 | id ; HW_REG_XCC_ID = 20 (gfx940+)
#define XCC_ID_REG (((4 - 1) << 11) | 20)

__device__ __forceinline__ float lrelu_exp(float v) {
    v = v > 0.f ? v : NEG_SLOPE * v;
    return __expf(v);
}

// ---------- fused: layer-1 MFMA GEMM (+logits) on even blocks, sharded ELL fill on odd ----------
__global__ __launch_bounds__(256) void fused_gemm_fill(
    const float* __restrict__ X, const float* __restrict__ W, __half* __restrict__ H,
    const float* __restrict__ a_src, const float* __restrict__ a_dst,
    float* __restrict__ als, float* __restrict__ ald,
    const int* __restrict__ src, const int* __restrict__ dst,
    int* __restrict__ cursor, int* __restrict__ ell) {
    __shared__ _Float16 wT[IN_C * 136];
    const int bid = blockIdx.x;
    const int t = threadIdx.x;

    if (bid & 1) {
        // fill role: XCD-local shard => single-writer cache lines
        const int xcc = __builtin_amdgcn_s_getreg(XCC_ID_REG) & 7;
        int* cur = cursor + xcc * N_NODES;
        int* es = ell + (size_t)xcc * N_NODES * SHW;
        const int tid = (bid >> 1) * 256 + t;
        if (tid < E_EDGES / 4) {
            const int4 s4 = ((const int4*)src)[tid];
            const int4 d4 = ((const int4*)dst)[tid];
            const int p0 = atomicAdd(&cur[d4.x], 1);
            const int p1 = atomicAdd(&cur[d4.y], 1);
            const int p2 = atomicAdd(&cur[d4.z], 1);
            const int p3 = atomicAdd(&cur[d4.w], 1);
            if (p0 < SHW) es[d4.x * SHW + p0] = s4.x;
            if (p1 < SHW) es[d4.y * SHW + p1] = s4.y;
            if (p2 < SHW) es[d4.z * SHW + p2] = s4.z;
            if (p3 < SHW) es[d4.w * SHW + p3] = s4.w;
        }
        return;
    }

    // gemm role: mfma_f32_16x16x32_f16, one wave = 16 rows x 128 cols
    for (int f = t * 4; f < IN_C * IN_C; f += 1024) {
        const float4 w4 = *(const float4*)&W[f];
        const int k = f >> 7, col = f & 127;
        wT[(col + 0) * 136 + k] = (_Float16)w4.x;
        wT[(col + 1) * 136 + k] = (_Float16)w4.y;
        wT[(col + 2) * 136 + k] = (_Float16)w4.z;
        wT[(col + 3) * 136 + k] = (_Float16)w4.w;
    }
    __syncthreads();

    const int wave = t >> 6, lane = t & 63;
    const int m = lane & 15, quad = lane >> 4;
    const int r0w = (bid >> 1) * 64 + wave * 16;
    int rl = r0w + m;
    if (rl >= N_NODES) rl = N_NODES - 1;
    const float* Xr = X + (size_t)rl * IN_C;

    floatx4 acc[8];
#pragma unroll
    for (int i = 0; i < 8; ++i) acc[i] = (floatx4){0.f, 0.f, 0.f, 0.f};

#pragma unroll
    for (int kc = 0; kc < 4; ++kc) {
        const int k8 = kc * 32 + quad * 8;
        const float4 xa = *(const float4*)(Xr + k8);
        const float4 xb = *(const float4*)(Xr + k8 + 4);
        half8 a;
        a[0] = (_Float16)xa.x; a[1] = (_Float16)xa.y;
        a[2] = (_Float16)xa.z; a[3] = (_Float16)xa.w;
        a[4] = (_Float16)xb.x; a[5] = (_Float16)xb.y;
        a[6] = (_Float16)xb.z; a[7] = (_Float16)xb.w;
#pragma unroll
        for (int ct = 0; ct < 8; ++ct) {
            const half8 b = *(const half8*)&wT[(ct * 16 + m) * 136 + k8];
            acc[ct] = __builtin_amdgcn_mfma_f32_16x16x32_f16(a, b, acc[ct], 0, 0, 0);
        }
    }

    _Float16* Hh = (_Float16*)H;
#pragma unroll
    for (int ct = 0; ct < 8; ++ct) {
        const float asv = a_src[ct * 16 + m];
        const float adv = a_dst[ct * 16 + m];
#pragma unroll
        for (int r = 0; r < 4; ++r) {
            const int row = r0w + quad * 4 + r;
            const float c = acc[ct][r];
            float ps = c * asv, pd = c * adv;
            ps += __shfl_xor(ps, 1); pd += __shfl_xor(pd, 1);
            ps += __shfl_xor(ps, 2); pd += __shfl_xor(pd, 2);
            ps += __shfl_xor(ps, 4); pd += __shfl_xor(pd, 4);
            ps += __shfl_xor(ps, 8); pd += __shfl_xor(pd, 8);
            if (row < N_NODES) {
                Hh[(size_t)row * IN_C + ct * 16 + m] = (_Float16)c;
                if (m == 0) {
                    als[(size_t)row * HEADS + ct] = ps;
                    ald[(size_t)row * HEADS + ct] = pd;
                }
            }
        }
    }
}

// ---------- compact: 8 shards -> one contiguous ELL row + total count ----------
// 8 lanes per node (one per shard); shuffle prefix-sum for bases.
__global__ __launch_bounds__(256) void compact_ell(
    const int* __restrict__ cursor, const int* __restrict__ ell_sh,
    int* __restrict__ cnt_tot, int* __restrict__ ell_c) {
    const int gt = blockIdx.x * 256 + threadIdx.x;
    const int n = gt >> 3, sh = gt & 7;
    if (n >= N_NODES) return;
    int c = cursor[sh * N_NODES + n];
    c = c < SHW ? c : SHW;
    int pre = c;
#pragma unroll
    for (int off = 1; off < 8; off <<= 1) {
        int v = __shfl_up(pre, off, 8);
        if ((threadIdx.x & 7) >= off) pre += v;
    }
    const int base = pre - c;
    if (sh == 7) cnt_tot[n] = pre;
    const int* inp = ell_sh + ((size_t)sh * N_NODES + n) * SHW;
    int* outp = ell_c + (size_t)n * CELLW + base;
    for (int j = 0; j < c; j += 4) {
        const int4 v = *(const int4*)(inp + j);  // shard rows 96B: 16B-aligned steps
        outp[j] = v.x;
        if (j + 1 < c) outp[j + 1] = v.y;
        if (j + 2 < c) outp[j + 2] = v.z;
        if (j + 3 < c) outp[j + 3] = v.w;
    }
}

// ---------- fused agg1 + gemm2 + logits2; 8 lanes/node (lane = head), 32 nodes/block ----------
__global__ __launch_bounds__(256) void agg1_gemm2(
    const int* __restrict__ cnt, const int* __restrict__ ell,
    const float* __restrict__ als, const float* __restrict__ ald,
    const __half* __restrict__ H, const float* __restrict__ b,
    const float* __restrict__ W2, const float* __restrict__ a2_src,
    const float* __restrict__ a2_dst, __half* __restrict__ H2,
    float* __restrict__ als2, float* __restrict__ ald2) {
    __shared__ _Float16 wsh[IN_C * OUT_C];  // 16 KB
    __shared__ float xrow[32 * 132];        // 16.9 KB
    const int t = threadIdx.x;
    for (int f = t * 4; f < IN_C * OUT_C; f += 1024) {
        const float4 w4 = *(const float4*)&W2[f];
        wsh[f + 0] = (_Float16)w4.x;
        wsh[f + 1] = (_Float16)w4.y;
        wsh[f + 2] = (_Float16)w4.z;
        wsh[f + 3] = (_Float16)w4.w;
    }

    // ---- Phase A: per-(node, head) gather over compact ELL ----
    const int nl = t >> 3, h = t & 7;
    int nc = blockIdx.x * 32 + nl;
    if (nc >= N_NODES) nc = N_NODES - 1;  // clamp; LDS-only writes, phase B guards stores
    const int deg = cnt[nc];
    const int* ep = ell + (size_t)nc * CELLW;
    const float ad = ald[nc * HEADS + h];
    float accv[16];
    float ssum;
    {
        const float w = lrelu_exp(als[nc * HEADS + h] + ad);  // self-loop
        const half8* q = (const half8*)(H + ((size_t)nc * HEADS + h) * HID);
        const half8 u0 = q[0], u1 = q[1];
        ssum = w;
#pragma unroll
        for (int j = 0; j < 8; ++j) {
            accv[j] = w * (float)u0[j];
            accv[j + 8] = w * (float)u1[j];
        }
    }
    for (int p = 0; p < deg; p += 4) {
        const int4 s4 = *(const int4*)(ep + p);
        const int i1 = (p + 1 < deg) ? s4.y : nc;
        const int i2 = (p + 2 < deg) ? s4.z : nc;
        const int i3 = (p + 3 < deg) ? s4.w : nc;
        const float f1 = (p + 1 < deg) ? 1.f : 0.f;
        const float f2 = (p + 2 < deg) ? 1.f : 0.f;
        const float f3 = (p + 3 < deg) ? 1.f : 0.f;
        const float v0 = als[s4.x * HEADS + h];
        const float v1 = als[i1 * HEADS + h];
        const float v2 = als[i2 * HEADS + h];
        const float v3 = als[i3 * HEADS + h];
        const half8* q0 = (const half8*)(H + ((size_t)s4.x * HEADS + h) * HID);
        const half8* q1 = (const half8*)(H + ((size_t)i1 * HEADS + h) * HID);
        const half8* q2 = (const half8*)(H + ((size_t)i2 * HEADS + h) * HID);
        const half8* q3 = (const half8*)(H + ((size_t)i3 * HEADS + h) * HID);
        const half8 a0 = q0[0], b0 = q0[1];
        const half8 a1 = q1[0], b1 = q1[1];
        const half8 a2 = q2[0], b2 = q2[1];
        const half8 a3 = q3[0], b3 = q3[1];
        const float w0 = lrelu_exp(v0 + ad);
        const float w1 = lrelu_exp(v1 + ad) * f1;
        const float w2 = lrelu_exp(v2 + ad) * f2;
        const float w3 = lrelu_exp(v3 + ad) * f3;
        ssum += (w0 + w1) + (w2 + w3);
#pragma unroll
        for (int j = 0; j < 8; ++j) {
            accv[j]     += w0 * (float)a0[j] + w1 * (float)a1[j] +
                           w2 * (float)a2[j] + w3 * (float)a3[j];
            accv[j + 8] += w0 * (float)b0[j] + w1 * (float)b1[j] +
                           w2 * (float)b2[j] + w3 * (float)b3[j];
        }
    }
    {
        const float inv = 1.f / (ssum + 1e-16f);
        float* xr = &xrow[nl * 132 + h * 16];
#pragma unroll
        for (int j = 0; j < 16; ++j) {
            float r = accv[j] * inv + b[h * 16 + j];
            xr[j] = r > 0.f ? r : 0.f;
        }
    }

    __syncthreads();

    // ---- Phase B: h2 = xrow @ W2 (8 cols/thread) + fused logits2 ----
    const int ng = t >> 3, jc = t & 7, j0 = jc * 8;
    const int n2 = blockIdx.x * 32 + ng;
    float o[8] = {};
    const float* xb = &xrow[ng * 132];
#pragma unroll 2
    for (int c = 0; c < IN_C; ++c) {
        const float xv = xb[c];
        const half8 wv = *(const half8*)&wsh[c * OUT_C + j0];
#pragma unroll
        for (int k = 0; k < 8; ++k) o[k] += xv * (float)wv[k];
    }
    float ps = 0.f, pd = 0.f;
#pragma unroll
    for (int k = 0; k < 8; ++k) {
        ps += o[k] * a2_src[j0 + k];
        pd += o[k] * a2_dst[j0 + k];
    }
    ps += __shfl_xor(ps, 1); pd += __shfl_xor(pd, 1);
    ps += __shfl_xor(ps, 2); pd += __shfl_xor(pd, 2);
    ps += __shfl_xor(ps, 4); pd += __shfl_xor(pd, 4);
    if (n2 < N_NODES) {
        half8 hv;
#pragma unroll
        for (int k = 0; k < 8; ++k) hv[k] = (_Float16)o[k];
        *(half8*)((_Float16*)H2 + (size_t)n2 * OUT_C + j0) = hv;
        if (jc == 0) {
            als2[n2] = ps;
            ald2[n2] = pd;
        }
    }
}

// ---------- agg2: 8 lanes/node, 8 ch/lane, compact ELL + analytic self-loop ----------
__global__ __launch_bounds__(256) void agg2(
    const int* __restrict__ cnt, const int* __restrict__ ell,
    const float* __restrict__ als, const float* __restrict__ ald,
    const __half* __restrict__ H, const float* __restrict__ b,
    float* __restrict__ out) {
    const int t = threadIdx.x;
    int n = blockIdx.x * 32 + (t >> 3);
    const int j0 = (t & 7) * 8;
    const bool valid = n < N_NODES;
    if (!valid) n = N_NODES - 1;
    const int deg = cnt[n];
    const int* ep = ell + (size_t)n * CELLW;
    const float ad = ald[n];
    float accv[8];
    float ssum;
    {
        const float w = lrelu_exp(als[n] + ad);
        const half8 u = *(const half8*)(H + (size_t)n * OUT_C + j0);
        ssum = w;
#pragma unroll
        for (int k = 0; k < 8; ++k) accv[k] = w * (float)u[k];
    }
    for (int p = 0; p < deg; p += 4) {
        const int4 s4 = *(const int4*)(ep + p);
        const int i1 = (p + 1 < deg) ? s4.y : n;
        const int i2 = (p + 2 < deg) ? s4.z : n;
        const int i3 = (p + 3 < deg) ? s4.w : n;
        const float f1 = (p + 1 < deg) ? 1.f : 0.f;
        const float f2 = (p + 2 < deg) ? 1.f : 0.f;
        const float f3 = (p + 3 < deg) ? 1.f : 0.f;
        const float v0 = als[s4.x];
        const float v1 = als[i1];
        const float v2 = als[i2];
        const float v3 = als[i3];
        const half8 u0 = *(const half8*)(H + (size_t)s4.x * OUT_C + j0);
        const half8 u1 = *(const half8*)(H + (size_t)i1 * OUT_C + j0);
        const half8 u2 = *(const half8*)(H + (size_t)i2 * OUT_C + j0);
        const half8 u3 = *(const half8*)(H + (size_t)i3 * OUT_C + j0);
        const float w0 = lrelu_exp(v0 + ad);
        const float w1 = lrelu_exp(v1 + ad) * f1;
        const float w2 = lrelu_exp(v2 + ad) * f2;
        const float w3 = lrelu_exp(v3 + ad) * f3;
        ssum += (w0 + w1) + (w2 + w3);
#pragma unroll
        for (int k = 0; k < 8; ++k)
            accv[k] += w0 * (float)u0[k] + w1 * (float)u1[k] +
                       w2 * (float)u2[k] + w3 * (float)u3[k];
    }
    if (valid) {
        const float inv = 1.f / (ssum + 1e-16f);
        float4 r0, r1;
        r0.x = accv[0] * inv + b[j0 + 0]; r0.y = accv[1] * inv + b[j0 + 1];
        r0.z = accv[2] * inv + b[j0 + 2]; r0.w = accv[3] * inv + b[j0 + 3];
        r1.x = accv[4] * inv + b[j0 + 4]; r1.y = accv[5] * inv + b[j0 + 5];
        r1.z = accv[6] * inv + b[j0 + 6]; r1.w = accv[7] * inv + b[j0 + 7];
        float* op = out + (size_t)n * OUT_C + j0;
        *(float4*)op = r0;
        *(float4*)(op + 4) = r1;
    }
}

extern "C" void kernel_launch(void* const* d_in, const int* in_sizes, int n_in,
                              void* d_out, int out_size, void* d_ws, size_t ws_size,
                              hipStream_t stream) {
    const float* x      = (const float*)d_in[0];
    const int*   ei     = (const int*)d_in[1];
    const float* W1     = (const float*)d_in[2];
    const float* a1_src = (const float*)d_in[3];
    const float* a1_dst = (const float*)d_in[4];
    const float* b1     = (const float*)d_in[5];
    const float* W2     = (const float*)d_in[6];
    const float* a2_src = (const float*)d_in[7];
    const float* a2_dst = (const float*)d_in[8];
    const float* b2     = (const float*)d_in[9];
    const int* src = ei;
    const int* dst = ei + E_EDGES;
    float* outp = (float*)d_out;

    // ---- workspace layout (16B-aligned) ----
    char* wsb = (char*)d_ws;
    __half* h1   = (__half*)wsb;                                 // N*128 f16
    __half* h2   = h1 + (size_t)N_NODES * IN_C;                  // N*64  f16
    float*  als1 = (float*)(h2 + (size_t)N_NODES * OUT_C);       // N*8
    float*  ald1 = als1 + N_NODES * HEADS;                       // N*8
    float*  als2 = ald1 + N_NODES * HEADS;                       // N
    float*  ald2 = als2 + N_NODES;                               // N
    int*    cursor  = (int*)(ald2 + N_NODES);                    // 8*N [zero]
    int*    ell_sh  = cursor + NSHARD * N_NODES;                 // 8*N*SHW
    int*    cnt_tot = ell_sh + (size_t)NSHARD * N_NODES * SHW;   // N
    int*    ell_c   = cnt_tot + N_NODES;                         // N*CELLW

    hipMemsetAsync(cursor, 0, NSHARD * N_NODES * sizeof(int), stream);

    // ---- fused layer-1 MFMA GEMM + sharded ELL fill ----
    {
        const int gemm_blocks = (N_NODES + 63) / 64;  // 782 (== fill blocks)
        fused_gemm_fill<<<gemm_blocks * 2, 256, 0, stream>>>(
            x, W1, h1, a1_src, a1_dst, als1, ald1, src, dst, cursor, ell_sh);
    }

    // ---- compact shards -> contiguous ELL ----
    compact_ell<<<(N_NODES * 8 + 255) / 256, 256, 0, stream>>>(cursor, ell_sh,
                                                               cnt_tot, ell_c);

    // ---- fused agg1 + gemm2 + logits2 ----
    agg1_gemm2<<<(N_NODES + 31) / 32, 256, 0, stream>>>(
        cnt_tot, ell_c, als1, ald1, h1, b1, W2, a2_src, a2_dst, h2, als2, ald2);

    // ---- layer-2 aggregation -> output ----
    agg2<<<(N_NODES + 31) / 32, 256, 0, stream>>>(cnt_tot, ell_c, als2, ald2, h2, b2, outp);
}